// Round 2
// 168.389 us; speedup vs baseline: 1.0307x; 1.0307x over previous
//
#include <hip/hip_runtime.h>
#include <stdint.h>

// Round 12 (= r11 resubmitted; r11 bench died on container acquisition, not
// on the kernel): quad-gather + zero-segment fast path.
// fp32 in / fp32 out. d_out = box, boxy (each [8,1,1024,2048]).
// gt_up[y,x] == gt[y>>3, x>>3] (never materialized).
//
// vs r10: instead of a padded scalar image P (4 scattered scalar loads per
// pixel), precompute Q[y][x] = (P[y][x], P[y][x+1], P[y+1][x], P[y+1][x+1])
// — one global_load_dwordx4 per pixel + 3 v_cndmask selects, exploiting
// cx1 in {cx0,cx0+1}, cy1 in {cy0,cy0+1} (holds after int clamps; pad ring
// supplies zeros so no validity logic). Numerically identical to r10.
// Plus: 8-px segments provably all-zero (ix<-1 | ix>=2048 | iy<-1 | iy>=1024
// across the affine segment, checked at endpoints) skip all loads/blends.

typedef float vfloat4 __attribute__((ext_vector_type(4)));

constexpr int BATCH = 8;
constexpr int HI = 128, WI = 256;
constexpr int HO = 1024, WO = 2048;
constexpr size_t NPIX = (size_t)BATCH * HO * WO;   // 16777216 per output

// Quad image: row index r = cy0+1, cy0 in [-1,HI] -> QH=130
//             col index c = cx0+1, cx0 in [-1,WI] -> QW=258
constexpr int QH = HI + 2;
constexpr int QW = WI + 2;
constexpr size_t QIMG = (size_t)QH * QW;           // quads per image

__global__ __launch_bounds__(256) void pad4_kernel(
    const float* __restrict__ gt, vfloat4* __restrict__ Q)
{
    const int i = blockIdx.x * 256 + threadIdx.x;  // over BATCH*QIMG
    if (i >= (int)(BATCH * QIMG)) return;
    const int b = i / (int)QIMG;
    const int r = i - b * (int)QIMG;
    const int y = r / QW - 1;                      // [-1, HI+0] (pad coords)
    const int x = r - (r / QW) * QW - 1;           // [-1, WI+0]
    const float* __restrict__ g = gt + (size_t)b * (HI * WI);
    auto val = [&](int yy, int xx) -> float {
        return (yy >= 0 && yy < HI && xx >= 0 && xx < WI)
                   ? g[yy * WI + xx] : 0.0f;
    };
    vfloat4 q = { val(y, x), val(y, x + 1), val(y + 1, x), val(y + 1, x + 1) };
    Q[i] = q;
}

__global__ __launch_bounds__(256) void stn_kernel(
    const float* __restrict__ gt,     // [B, HI, WI] (boxy path)
    const float* __restrict__ theta,  // [B, 6]
    const vfloat4* __restrict__ Q,    // quad images in d_ws
    float* __restrict__ out)          // [2, B, HO, WO] f32
{
    const int row = blockIdx.x;            // b*HO + h
    const int b = row >> 10;
    const int h = row & (HO - 1);
    const int t = threadIdx.x;
    const int w0 = t << 3;

    const float* tb = theta + b * 6;
    const float t0 = tb[0], t1 = tb[1], t2 = tb[2];
    const float t3 = tb[3], t4 = tb[4], t5 = tb[5];
    const float* __restrict__ gtb = gt + b * (HI * WI);
    const vfloat4* __restrict__ Qb = Q + (size_t)b * QIMG;

    const float ys = (h + 0.5f) * (2.0f / (float)HO) - 1.0f;

    // ---------------- boxy: scalar per thread, broadcast to 8 px ----------------
    {
        const float gy2 = t4 * ys + t5;
        const float iy = ((gy2 + 1.0f) * (float)HO - 1.0f) * 0.5f;
        const float fy = floorf(iy);
        const float wy = iy - fy;
        const float vy0 = (fy >= 0.0f && fy <= (float)(HO - 1)) ? 1.0f : 0.0f;
        const float vy1 = (fy >= -1.0f && fy <= (float)(HO - 2)) ? 1.0f : 0.0f;
        const int y0 = ((int)fminf(fmaxf(fy,        0.0f), (float)(HO - 1))) >> 3;
        const int y1 = ((int)fminf(fmaxf(fy + 1.0f, 0.0f), (float)(HO - 1))) >> 3;
        const float s0 = gtb[y0 * WI + t];
        const float s1 = gtb[y1 * WI + t];
        const float byv = s0 * ((1.0f - wy) * vy0) + s1 * (wy * vy1);
        const vfloat4 vb = {byv, byv, byv, byv};
        vfloat4* dst = reinterpret_cast<vfloat4*>(out + NPIX + (size_t)row * WO + w0);
        __builtin_nontemporal_store(vb, dst);
        __builtin_nontemporal_store(vb, dst + 1);
    }

    // ---------------- box: 8 px bilinear via one quad load each ----------------
    const float xn0 = (w0 + 0.5f) * (2.0f / (float)WO) - 1.0f;
    const float gx0 = t0 * xn0 + (t1 * ys + t2);
    const float gy0 = t3 * xn0 + (t4 * ys + t5);
    float ix = ((gx0 + 1.0f) * (float)WO - 1.0f) * 0.5f;   // step t0 per px
    float iy = ((gy0 + 1.0f) * (float)HO - 1.0f) * 0.5f;   // step t3/2 per px
    const float dix = t0;
    const float diy = 0.5f * t3;

    // Zero-segment test: pixel is exactly 0 iff ix<-1 | ix>=WO | iy<-1 | iy>=HO.
    // ix,iy affine in p -> endpoint checks prove the whole 8-px segment zero.
    const float ixe = ix + 7.0f * dix;
    const float iye = iy + 7.0f * diy;
    const bool segzero =
        (fmaxf(ix, ixe) < -1.0f) || (fminf(ix, ixe) >= (float)WO) ||
        (fmaxf(iy, iye) < -1.0f) || (fminf(iy, iye) >= (float)HO);

    float px[8];
    if (segzero) {
#pragma unroll
        for (int p = 0; p < 8; ++p) px[p] = 0.0f;
    } else {
#pragma unroll
        for (int p = 0; p < 8; ++p) {
            const float fx = floorf(ix), fy = floorf(iy);
            const float wx = ix - fx,    wy = iy - fy;
            const int xi = (int)fx, yi = (int)fy;       // cvt saturates at extremes
            const int cx0 = min(max(xi >> 3,       -1), WI);
            const int cx1 = min(max((xi + 1) >> 3, -1), WI);
            const int cy0 = min(max(yi >> 3,       -1), HI);
            const int cy1 = min(max((yi + 1) >> 3, -1), HI);
            const vfloat4 q = Qb[(cy0 + 1) * QW + (cx0 + 1)];
            const bool cxe = (cx1 == cx0);
            const bool cye = (cy1 == cy0);
            const float a  = q.x;
            const float bb = cxe ? q.x : q.y;           // P[cy0][cx1]
            const float c  = cye ? q.x : q.z;           // P[cy1][cx0]
            const float dl = cxe ? q.z : q.w;
            const float d  = cye ? bb  : dl;            // P[cy1][cx1]
            const float h0 = fmaf(wx, bb - a, a);
            const float h1 = fmaf(wx, d - c,  c);
            px[p] = fmaf(wy, h1 - h0, h0);
            ix += dix; iy += diy;
        }
    }
    vfloat4* dst = reinterpret_cast<vfloat4*>(out + (size_t)row * WO + w0);
    const vfloat4 v0 = {px[0], px[1], px[2], px[3]};
    const vfloat4 v1 = {px[4], px[5], px[6], px[7]};
    __builtin_nontemporal_store(v0, dst);
    __builtin_nontemporal_store(v1, dst + 1);
}

extern "C" void kernel_launch(void* const* d_in, const int* in_sizes, int n_in,
                              void* d_out, int out_size, void* d_ws, size_t ws_size,
                              hipStream_t stream) {
    const float* gt    = (const float*)d_in[0];
    const float* theta = (const float*)d_in[1];
    float* out = (float*)d_out;
    vfloat4* Q = (vfloat4*)d_ws;   // 8*130*258*16 B ~= 4.3 MB << ws_size

    const int qN = (int)(BATCH * QIMG);
    pad4_kernel<<<(qN + 255) / 256, 256, 0, stream>>>(gt, Q);
    stn_kernel<<<BATCH * HO, 256, 0, stream>>>(gt, theta, Q, out);
}